// Round 1
// baseline (2393.324 us; speedup 1.0000x reference)
//
#include <hip/hip_runtime.h>
#include <hip/hip_bf16.h>
#include <cstdint>
#include <cstddef>

// ---------------- JAX threefry2x32 (partitionable scheme) ----------------
struct TF2 { uint32_t a, b; };

__host__ __device__ constexpr uint32_t rotl32(uint32_t v, int r) {
  return (v << r) | (v >> (32 - r));
}

__host__ __device__ constexpr TF2 threefry2x32(uint32_t k0, uint32_t k1,
                                               uint32_t x0, uint32_t x1) {
  uint32_t ks0 = k0, ks1 = k1, ks2 = k0 ^ k1 ^ 0x1BD11BDAu;
  const int rotA[4] = {13, 15, 26, 6};
  const int rotB[4] = {17, 29, 16, 24};
  x0 += ks0; x1 += ks1;
  for (int i = 0; i < 5; ++i) {
    const int* rot = (i % 2 == 0) ? rotA : rotB;
    for (int j = 0; j < 4; ++j) {
      x0 += x1; x1 = rotl32(x1, rot[j]); x1 ^= x0;
    }
    uint32_t ks[3] = {ks0, ks1, ks2};
    x0 += ks[(i + 1) % 3];
    x1 += ks[(i + 2) % 3] + (uint32_t)(i + 1);
  }
  return TF2{x0, x1};
}

// key(42) -> (0,42); split(key,3) foldlike: child i = threefry block at (0, i).
// bernoulli(k,0.7,shape): elem j -> bits = o0^o1 of threefry(k, (0,j));
// u = bitcast((bits>>9)|0x3f800000)-1; keep iff u < 0.7f; scaled by 1/0.7f.
__device__ __forceinline__ float jax_mask(uint32_t child, uint32_t idx) {
  TF2 ck = threefry2x32(0u, 42u, 0u, child);   // constant-folds
  TF2 r  = threefry2x32(ck.a, ck.b, 0u, idx);
  uint32_t bits = r.a ^ r.b;
  float u = __uint_as_float((bits >> 9) | 0x3f800000u) - 1.0f;
  return (u < 0.7f) ? (1.0f / 0.7f) : 0.0f;
}

// ---------------- build x = [image_emb ; emb_table[targets]*word_mask] ----
__global__ __launch_bounds__(256) void build_x_kernel(
    const float* __restrict__ img, const int* __restrict__ tgt,
    const float* __restrict__ emb, float* __restrict__ x) {
  const int idx = blockIdx.x * 256 + threadIdx.x;   // b*32768 + t*512 + e
  const int e = idx & 511;
  const int t = (idx >> 9) & 63;
  const int b = idx >> 15;
  float v;
  if (t == 0) {
    v = img[b * 512 + e];
  } else {
    const int w = tgt[b * 64 + (t - 1)];
    const float wm = jax_mask(0u, (uint32_t)(b * 512 + e)); // word mask (B,1,E)
    v = emb[(size_t)w * 512 + e] * wm;
  }
  x[idx] = v;
}

// ---------------- recurrent dropout masks (4,B,U), pre-scaled ------------
__global__ __launch_bounds__(256) void rec_mask_kernel(float* __restrict__ rm) {
  const int idx = blockIdx.x * 256 + threadIdx.x;   // g*16384 + b*512 + u
  rm[idx] = jax_mask(1u, (uint32_t)idx);
}

// ---------------- transpose W_rec (512x2048) -> WT (2048x512) ------------
__global__ __launch_bounds__(256) void transpose_wrec(
    const float* __restrict__ in, float* __restrict__ out) {
  __shared__ float tile[32][33];
  const int j0 = blockIdx.x * 32;
  const int u0 = blockIdx.y * 32;
  const int tx = threadIdx.x & 31;
  const int ty = threadIdx.x >> 5;   // 0..7
  for (int r = ty; r < 32; r += 8)
    tile[r][tx] = in[(size_t)(u0 + r) * 2048 + (j0 + tx)];
  __syncthreads();
  for (int r = ty; r < 32; r += 8)
    out[(size_t)(j0 + r) * 512 + (u0 + tx)] = tile[tx][r];
}

// ---------------- fp32 tiled GEMM: C = A[MxK] @ B[KxN] + bias[N] ---------
__global__ __launch_bounds__(256) void gemm_f32_64(
    const float* __restrict__ A, const float* __restrict__ Bm,
    const float* __restrict__ bias, float* __restrict__ C,
    int M, int N, int K) {
  __shared__ __align__(16) float As[16][68];   // [k][m]
  __shared__ __align__(16) float Bs[16][68];   // [k][n]
  const int tid = threadIdx.x;
  const int tx = tid & 15;
  const int ty = tid >> 4;
  const int n0 = blockIdx.x * 64;
  const int m0 = blockIdx.y * 64;

  const int ar = tid >> 2;          // 0..63
  const int ak = (tid & 3) << 2;    // 0,4,8,12
  const int bk = tid >> 4;          // 0..15
  const int bn = (tid & 15) << 2;   // 0..60

  float acc[4][4] = {};

  for (int k0 = 0; k0 < K; k0 += 16) {
    float4 av = *(const float4*)(A + (size_t)(m0 + ar) * K + (k0 + ak));
    float4 bv = *(const float4*)(Bm + (size_t)(k0 + bk) * N + (n0 + bn));
    As[ak + 0][ar] = av.x;
    As[ak + 1][ar] = av.y;
    As[ak + 2][ar] = av.z;
    As[ak + 3][ar] = av.w;
    *(float4*)&Bs[bk][bn] = bv;
    __syncthreads();
#pragma unroll
    for (int kk = 0; kk < 16; ++kk) {
      float4 a = *(const float4*)&As[kk][ty * 4];
      float4 b = *(const float4*)&Bs[kk][tx * 4];
      const float aa[4] = {a.x, a.y, a.z, a.w};
      const float bb[4] = {b.x, b.y, b.z, b.w};
#pragma unroll
      for (int i = 0; i < 4; ++i)
#pragma unroll
        for (int j = 0; j < 4; ++j)
          acc[i][j] += aa[i] * bb[j];
    }
    __syncthreads();
  }
#pragma unroll
  for (int i = 0; i < 4; ++i) {
    const int row = m0 + ty * 4 + i;
    const int col = n0 + tx * 4;
    float4 o;
    o.x = acc[i][0] + bias[col + 0];
    o.y = acc[i][1] + bias[col + 1];
    o.z = acc[i][2] + bias[col + 2];
    o.w = acc[i][3] + bias[col + 3];
    *(float4*)(C + (size_t)row * N + col) = o;
  }
}

// ---------------- one LSTM time step -------------------------------------
// grid 512 = 64 v-slices x 8 b-groups(4 b each); block 128 = 8v x 4g x 4b.
// hmr: masked-h state (4,B,U) from previous step (read); hmw: written.
__global__ __launch_bounds__(128) void lstm_step_kernel(
    const float* __restrict__ z_in, const float* __restrict__ WT,
    const float* __restrict__ rm, const float* __restrict__ hmr,
    float* __restrict__ hmw, float* __restrict__ c,
    float* __restrict__ rnn_out, const int t) {
  __shared__ __align__(16) float hm_s[4][4][516];   // [b_local][g][u]
  __shared__ float zs[4][4][8];                     // [b_local][g][v]
  const int tid = threadIdx.x;
  const int v  = tid & 7;
  const int g  = (tid >> 3) & 3;
  const int bl = tid >> 5;                   // 0..3
  const int v0 = (blockIdx.x & 63) * 8;
  const int b0 = (blockIdx.x >> 6) * 4;
  const int b  = b0 + bl;

  {  // stage masked-h for this block's 4 batch rows, all 4 gates
    const float* src = hmr + ((size_t)g * 32 + b) * 512;
    float* dst = &hm_s[bl][g][0];
#pragma unroll
    for (int i = 0; i < 16; ++i) {
      const int u = i * 32 + v * 4;
      *(float4*)&dst[u] = *(const float4*)&src[u];
    }
  }
  __syncthreads();

  const int j = g * 512 + v0 + v;            // column of W_rec
  const float4* __restrict__ wt4 = (const float4*)(WT + (size_t)j * 512);
  const float4* __restrict__ hv4 = (const float4*)&hm_s[bl][g][0];
  float acc = 0.f;
#pragma unroll 8
  for (int i = 0; i < 128; ++i) {
    const float4 w  = wt4[i];
    const float4 hh = hv4[i];
    acc += w.x * hh.x + w.y * hh.y + w.z * hh.z + w.w * hh.w;
  }
  zs[bl][g][v] = z_in[((size_t)b * 64 + t) * 2048 + j] + acc;
  __syncthreads();

  if (tid < 32) {                            // 4 b x 8 v combine
    const int vv = tid & 7;
    const int bb = tid >> 3;
    const int bg = b0 + bb;
    const int vg = v0 + vv;
    const float zi = zs[bb][0][vv];
    const float zf = zs[bb][1][vv];
    const float zg = zs[bb][2][vv];
    const float zo = zs[bb][3][vv];
    const float i_ = 1.f / (1.f + expf(-zi));
    const float f_ = 1.f / (1.f + expf(-zf));
    const float g_ = tanhf(zg);
    const float o_ = 1.f / (1.f + expf(-zo));
    const size_t cidx = (size_t)bg * 512 + vg;
    const float cn = f_ * c[cidx] + i_ * g_;
    const float hn = o_ * tanhf(cn);
    c[cidx] = cn;
    const float fmask = jax_mask(2u, (uint32_t)((bg * 64 + t) * 512 + vg));
    rnn_out[((size_t)bg * 64 + t) * 512 + vg] = hn * fmask;
#pragma unroll
    for (int gg = 0; gg < 4; ++gg) {
      const size_t o = ((size_t)gg * 32 + bg) * 512 + vg;
      hmw[o] = hn * rm[o];
    }
  }
}

// ---------------- launch -------------------------------------------------
extern "C" void kernel_launch(void* const* d_in, const int* in_sizes, int n_in,
                              void* d_out, int out_size, void* d_ws, size_t ws_size,
                              hipStream_t stream) {
  (void)in_sizes; (void)n_in; (void)out_size; (void)ws_size;
  const float* img   = (const float*)d_in[1];
  const int*   tgt   = (const int*)d_in[2];
  const float* emb   = (const float*)d_in[3];
  const float* W_in  = (const float*)d_in[4];
  const float* W_rec = (const float*)d_in[5];
  const float* b_l   = (const float*)d_in[6];
  const float* W_out = (const float*)d_in[7];
  const float* b_o   = (const float*)d_in[8];
  float* out = (float*)d_out;
  float* ws  = (float*)d_ws;

  float* x    = ws;                 // 1,048,576
  float* zin  = ws + 1048576;       // 4,194,304
  float* rnn  = ws + 5242880;       // 1,048,576
  float* hm0  = ws + 6291456;       //    65,536
  float* c    = ws + 6356992;       //    16,384
  float* hm1  = ws + 6373376;       //    65,536
  float* rm   = ws + 6438912;       //    65,536
  float* WT   = ws + 6504448;       // 1,048,576  (total ~28.8 MiB)

  // zero initial state: hm0 (masked h0 = 0) and c, contiguous region
  hipMemsetAsync(hm0, 0, (size_t)(65536 + 16384) * sizeof(float), stream);

  build_x_kernel<<<4096, 256, 0, stream>>>(img, tgt, emb, x);
  rec_mask_kernel<<<256, 256, 0, stream>>>(rm);
  transpose_wrec<<<dim3(64, 16), 256, 0, stream>>>(W_rec, WT);

  // z_in = x @ W_in + b_lstm   (2048 x 512) @ (512 x 2048)
  gemm_f32_64<<<dim3(32, 32), 256, 0, stream>>>(x, W_in, b_l, zin, 2048, 2048, 512);

  for (int t = 0; t < 64; ++t) {
    const float* hr = (t & 1) ? hm1 : hm0;
    float*       hw = (t & 1) ? hm0 : hm1;
    lstm_step_kernel<<<512, 128, 0, stream>>>(zin, WT, rm, hr, hw, c, rnn, t);
  }

  // predictions = rnn_out @ W_out + b_out   (2048 x 512) @ (512 x 32000)
  gemm_f32_64<<<dim3(500, 32), 256, 0, stream>>>(rnn, W_out, b_o, out, 2048, 32000, 512);
}

// Round 2
// 1088.871 us; speedup vs baseline: 2.1980x; 2.1980x over previous
//
#include <hip/hip_runtime.h>
#include <hip/hip_bf16.h>
#include <cstdint>
#include <cstddef>

// ---------------- JAX threefry2x32 (partitionable scheme) — FROZEN (verified R1)
struct TF2 { uint32_t a, b; };

__host__ __device__ constexpr uint32_t rotl32(uint32_t v, int r) {
  return (v << r) | (v >> (32 - r));
}

__host__ __device__ constexpr TF2 threefry2x32(uint32_t k0, uint32_t k1,
                                               uint32_t x0, uint32_t x1) {
  uint32_t ks0 = k0, ks1 = k1, ks2 = k0 ^ k1 ^ 0x1BD11BDAu;
  const int rotA[4] = {13, 15, 26, 6};
  const int rotB[4] = {17, 29, 16, 24};
  x0 += ks0; x1 += ks1;
  for (int i = 0; i < 5; ++i) {
    const int* rot = (i % 2 == 0) ? rotA : rotB;
    for (int j = 0; j < 4; ++j) {
      x0 += x1; x1 = rotl32(x1, rot[j]); x1 ^= x0;
    }
    uint32_t ks[3] = {ks0, ks1, ks2};
    x0 += ks[(i + 1) % 3];
    x1 += ks[(i + 2) % 3] + (uint32_t)(i + 1);
  }
  return TF2{x0, x1};
}

__device__ __forceinline__ float jax_mask(uint32_t child, uint32_t idx) {
  TF2 ck = threefry2x32(0u, 42u, 0u, child);   // constant-folds
  TF2 r  = threefry2x32(ck.a, ck.b, 0u, idx);
  uint32_t bits = r.a ^ r.b;
  float u = __uint_as_float((bits >> 9) | 0x3f800000u) - 1.0f;
  return (u < 0.7f) ? (1.0f / 0.7f) : 0.0f;
}

__device__ __forceinline__ unsigned short f2bf(float f) {
  uint32_t u = __float_as_uint(f);
  uint32_t r = (u + 0x7fffu + ((u >> 16) & 1u)) >> 16;   // RNE
  return (unsigned short)r;
}

typedef __attribute__((ext_vector_type(8))) short short8;
typedef __attribute__((ext_vector_type(4))) float f32x4;

// async global->LDS, 16B per lane. LDS dest = wave-uniform base + lane*16.
__device__ __forceinline__ void async_copy16(const unsigned short* g, unsigned short* l) {
  __builtin_amdgcn_global_load_lds(
      (const __attribute__((address_space(1))) unsigned int*)g,
      (__attribute__((address_space(3))) unsigned int*)l, 16, 0, 0);
}

// ---------------- build x (bf16) = [image_emb ; emb_table[targets]*word_mask]
__global__ __launch_bounds__(256) void build_x_kernel(
    const float* __restrict__ img, const int* __restrict__ tgt,
    const float* __restrict__ emb, unsigned short* __restrict__ x) {
  const int idx = blockIdx.x * 256 + threadIdx.x;   // b*32768 + t*512 + e
  const int e = idx & 511;
  const int t = (idx >> 9) & 63;
  const int b = idx >> 15;
  float v;
  if (t == 0) {
    v = img[b * 512 + e];
  } else {
    const int w = tgt[b * 64 + (t - 1)];
    const float wm = jax_mask(0u, (uint32_t)(b * 512 + e));
    v = emb[(size_t)w * 512 + e] * wm;
  }
  x[idx] = f2bf(v);
}

// ---------------- recurrent dropout masks (4,B,U), pre-scaled ------------
__global__ __launch_bounds__(256) void rec_mask_kernel(float* __restrict__ rm) {
  const int idx = blockIdx.x * 256 + threadIdx.x;
  rm[idx] = jax_mask(1u, (uint32_t)idx);
}

// ---------------- transpose W_rec (512x2048) -> WT (2048x512) fp32 -------
__global__ __launch_bounds__(256) void transpose_wrec(
    const float* __restrict__ in, float* __restrict__ out) {
  __shared__ float tile[32][33];
  const int j0 = blockIdx.x * 32;
  const int u0 = blockIdx.y * 32;
  const int tx = threadIdx.x & 31;
  const int ty = threadIdx.x >> 5;
  for (int r = ty; r < 32; r += 8)
    tile[r][tx] = in[(size_t)(u0 + r) * 2048 + (j0 + tx)];
  __syncthreads();
  for (int r = ty; r < 32; r += 8)
    out[(size_t)(j0 + r) * 512 + (u0 + tx)] = tile[tx][r];
}

// ------- transpose+convert fp32 [R][C] -> bf16 [C][R]  (R=512 here) ------
__global__ __launch_bounds__(256) void transpose_cvt(
    const float* __restrict__ in, unsigned short* __restrict__ out,
    int R, int C) {
  __shared__ float tile[32][33];
  const int c0 = blockIdx.x * 32;
  const int r0 = blockIdx.y * 32;
  const int tx = threadIdx.x & 31;
  const int ty = threadIdx.x >> 5;
  for (int r = ty; r < 32; r += 8)
    tile[r][tx] = in[(size_t)(r0 + r) * C + (c0 + tx)];
  __syncthreads();
  for (int r = ty; r < 32; r += 8)
    out[(size_t)(c0 + r) * R + (r0 + tx)] = f2bf(tile[tx][r]);
}

// ---------------- bf16 MFMA GEMM: C[M][N] = A[M][512] * BT[N][512]^T + bias
// 128x128 tile, BK=32, 16x16x32 MFMA, fp32 accum. m97 structure.
__global__ __launch_bounds__(256) void gemm_bf16_mfma(
    const unsigned short* __restrict__ A, const unsigned short* __restrict__ BT,
    const float* __restrict__ bias, float* __restrict__ C, int M, int N) {
  __shared__ unsigned short As[128 * 32];   // [m][k] rows of 32 bf16 (64B)
  __shared__ unsigned short Bs[128 * 32];   // [n][k]
  const int tid = threadIdx.x;
  const int lane = tid & 63;
  const int wave = tid >> 6;              // 0..3
  const int wm = (wave >> 1) * 64;
  const int wn = (wave & 1) * 64;
  const int m0 = blockIdx.y * 128;
  const int n0 = blockIdx.x * 128;

  f32x4 zero4 = {0.f, 0.f, 0.f, 0.f};
  f32x4 acc[4][4];
#pragma unroll
  for (int i = 0; i < 4; ++i)
#pragma unroll
    for (int j = 0; j < 4; ++j) acc[i][j] = zero4;

  // staging: thread covers row tid/4 (and +64), 16B chunk tid%4
  const unsigned short* ga = A + (size_t)(m0 + (tid >> 2)) * 512 + (tid & 3) * 8;
  const unsigned short* gb = BT + (size_t)(n0 + (tid >> 2)) * 512 + (tid & 3) * 8;
  unsigned short* lwA = As + wave * 512;   // + lane*16B by HW
  unsigned short* lwB = Bs + wave * 512;

  const int fr = lane & 15;
  const int kc = (lane >> 4) * 8;

  for (int k0 = 0; k0 < 512; k0 += 32) {
    __syncthreads();   // previous frag reads done before overwrite
    async_copy16(ga + k0, lwA);
    async_copy16(ga + k0 + 64 * 512, lwA + 2048);
    async_copy16(gb + k0, lwB);
    async_copy16(gb + k0 + 64 * 512, lwB + 2048);
    __syncthreads();   // drain vmcnt: LDS tiles ready

    short8 af[4], bf[4];
#pragma unroll
    for (int i = 0; i < 4; ++i)
      af[i] = *(const short8*)(As + (wm + i * 16 + fr) * 32 + kc);
#pragma unroll
    for (int i = 0; i < 4; ++i)
      bf[i] = *(const short8*)(Bs + (wn + i * 16 + fr) * 32 + kc);
#pragma unroll
    for (int mi = 0; mi < 4; ++mi)
#pragma unroll
      for (int ni = 0; ni < 4; ++ni)
        acc[mi][ni] = __builtin_amdgcn_mfma_f32_16x16x32_bf16(
            af[mi], bf[ni], acc[mi][ni], 0, 0, 0);
  }

  // epilogue: C row = quad*4+reg, col = lane&15 (m89-verified layout)
#pragma unroll
  for (int mi = 0; mi < 4; ++mi) {
    const int mrow = m0 + wm + mi * 16 + (lane >> 4) * 4;
#pragma unroll
    for (int ni = 0; ni < 4; ++ni) {
      const int ncol = n0 + wn + ni * 16 + (lane & 15);
      const float bs = bias[ncol];
#pragma unroll
      for (int r2 = 0; r2 < 4; ++r2)
        C[(size_t)(mrow + r2) * N + ncol] = acc[mi][ni][r2] + bs;
    }
  }
}

// ---------------- one LSTM time step (v3) --------------------------------
// grid 256 = 64 u-tiles x 4 b-groups; block 256 = (4g x 8u) x 8b, 1 out/thread.
// W rows + masked-h rows staged in LDS in 4 k-phases of 128 (~35 KB LDS).
__global__ __launch_bounds__(256) void lstm_step2(
    const float* __restrict__ zin, const float* __restrict__ WT,
    const float* __restrict__ rm, const float* __restrict__ hmr,
    float* __restrict__ hmw, float* __restrict__ c,
    unsigned short* __restrict__ rnn, const int t) {
  __shared__ __align__(16) float wl[32 * 132];   // row stride 132: 4-way-opt banks
  __shared__ __align__(16) float hl[32 * 132];
  __shared__ float zsh[4][8][9];
  const int tid = threadIdx.x;
  const int u0 = (blockIdx.x & 63) * 8;
  const int b0 = (blockIdx.x >> 6) * 8;

  const int jl = tid & 31;            // 4g x 8u
  const int bl = tid >> 5;            // 0..7
  const int g = jl >> 3, ul = jl & 7;
  const int b = b0 + bl;
  const float zv = zin[(size_t)(b * 64 + t) * 2048 + g * 512 + u0 + ul];

  // stage mapping: row srow = tid>>3 (0..31), 8 threads x 4 float4 per row
  const int srow = tid >> 3;
  const int sg = srow >> 3, sr = srow & 7;      // (g,u) for W; (g,b) for h
  const float* wsrc = WT + (size_t)(sg * 512 + u0 + sr) * 512;
  const float* hsrc = hmr + (size_t)(sg * 32 + b0 + sr) * 512;

  const float4* wp = (const float4*)&wl[jl * 132];
  const float4* hp = (const float4*)&hl[(g * 8 + bl) * 132];

  float4 a0 = {0.f, 0.f, 0.f, 0.f}, a1 = {0.f, 0.f, 0.f, 0.f};

  for (int ph = 0; ph < 4; ++ph) {
    const int kbase = ph * 128;
    __syncthreads();   // protect LDS from previous phase's readers
#pragma unroll
    for (int cc = 0; cc < 4; ++cc) {
      const int ch = (tid & 7) + cc * 8;        // 0..31 float4 chunks
      *(float4*)&wl[srow * 132 + ch * 4] = *(const float4*)&wsrc[kbase + ch * 4];
      *(float4*)&hl[srow * 132 + ch * 4] = *(const float4*)&hsrc[kbase + ch * 4];
    }
    __syncthreads();
#pragma unroll 8
    for (int i = 0; i < 32; i += 2) {
      const float4 w0 = wp[i], h0 = hp[i];
      const float4 w1 = wp[i + 1], h1 = hp[i + 1];
      a0.x += w0.x * h0.x; a0.y += w0.y * h0.y;
      a0.z += w0.z * h0.z; a0.w += w0.w * h0.w;
      a1.x += w1.x * h1.x; a1.y += w1.y * h1.y;
      a1.z += w1.z * h1.z; a1.w += w1.w * h1.w;
    }
  }
  const float dot = (a0.x + a0.y + a0.z + a0.w) + (a1.x + a1.y + a1.z + a1.w);
  zsh[g][bl][ul] = zv + dot;
  __syncthreads();

  if (tid < 64) {
    const int uu = tid & 7, bb = tid >> 3;
    const float zi = zsh[0][bb][uu];
    const float zf = zsh[1][bb][uu];
    const float zg = zsh[2][bb][uu];
    const float zo = zsh[3][bb][uu];
    const float i_ = 1.f / (1.f + expf(-zi));
    const float f_ = 1.f / (1.f + expf(-zf));
    const float g_ = tanhf(zg);
    const float o_ = 1.f / (1.f + expf(-zo));
    const int bg = b0 + bb, ug = u0 + uu;
    const size_t cidx = (size_t)bg * 512 + ug;
    const float cn = f_ * c[cidx] + i_ * g_;
    c[cidx] = cn;
    const float hn = o_ * tanhf(cn);
    const float fm = jax_mask(2u, (uint32_t)((bg * 64 + t) * 512 + ug));
    rnn[(size_t)(bg * 64 + t) * 512 + ug] = f2bf(hn * fm);
#pragma unroll
    for (int gg = 0; gg < 4; ++gg) {
      const size_t o = (size_t)(gg * 32 + bg) * 512 + ug;
      hmw[o] = hn * rm[o];
    }
  }
}

// ---------------- launch -------------------------------------------------
extern "C" void kernel_launch(void* const* d_in, const int* in_sizes, int n_in,
                              void* d_out, int out_size, void* d_ws, size_t ws_size,
                              hipStream_t stream) {
  (void)in_sizes; (void)n_in; (void)out_size; (void)ws_size;
  const float* img   = (const float*)d_in[1];
  const int*   tgt   = (const int*)d_in[2];
  const float* emb   = (const float*)d_in[3];
  const float* W_in  = (const float*)d_in[4];
  const float* W_rec = (const float*)d_in[5];
  const float* b_l   = (const float*)d_in[6];
  const float* W_out = (const float*)d_in[7];
  const float* b_o   = (const float*)d_in[8];
  float* out = (float*)d_out;
  float* ws  = (float*)d_ws;

  float* zin = ws;                       // 4,194,304 f
  float* WT  = ws + 4194304;             // 1,048,576 f
  float* hm0 = ws + 5242880;             //    65,536 f
  float* c   = ws + 5308416;             //    16,384 f
  float* hm1 = ws + 5324800;             //    65,536 f
  float* rm  = ws + 5390336;             //    65,536 f
  unsigned short* us = (unsigned short*)(ws + 5455872);
  unsigned short* x_bf  = us;            // 1,048,576 us (2 MB)
  unsigned short* WinT  = us + 1048576;  // 1,048,576 us
  unsigned short* rnn   = us + 2097152;  // 1,048,576 us
  unsigned short* WoutT = us + 3145728;  // 16,384,000 us (32.8 MB) — ~58 MB total

  hipMemsetAsync(hm0, 0, (size_t)(65536 + 16384) * sizeof(float), stream);

  build_x_kernel<<<4096, 256, 0, stream>>>(img, tgt, emb, x_bf);
  rec_mask_kernel<<<256, 256, 0, stream>>>(rm);
  transpose_wrec<<<dim3(64, 16), 256, 0, stream>>>(W_rec, WT);
  transpose_cvt<<<dim3(64, 16), 256, 0, stream>>>(W_in, WinT, 512, 2048);
  transpose_cvt<<<dim3(1000, 16), 256, 0, stream>>>(W_out, WoutT, 512, 32000);

  // z_in = x @ W_in + b_lstm : (2048x512)@(512x2048), bf16 MFMA
  gemm_bf16_mfma<<<dim3(16, 16), 256, 0, stream>>>(x_bf, WinT, b_l, zin, 2048, 2048);

  for (int t = 0; t < 64; ++t) {
    const float* hr = (t & 1) ? hm1 : hm0;
    float*       hw = (t & 1) ? hm0 : hm1;
    lstm_step2<<<256, 256, 0, stream>>>(zin, WT, rm, hr, hw, c, rnn, t);
  }

  // predictions = rnn_out @ W_out + b_out : (2048x512)@(512x32000), bf16 MFMA
  gemm_bf16_mfma<<<dim3(250, 16), 256, 0, stream>>>(rnn, WoutT, b_o, out, 2048, 32000);
}